// Round 2
// baseline (206.225 us; speedup 1.0000x reference)
//
#include <hip/hip_runtime.h>

// Non-local (SAGAN) block on MI355X. B=8, C=256, C'=64, N=4096.
// Round 8: flash restructured for LDS-pipe relief (was ~72% of CU cycles):
// 32x32x16 MFMA, swapped QK (S^T = K*Q^T) -> per-wave 32-row n-strip holds all
// 64 m in registers; P packed in-register via pk_trunc + permlane32_swap (T12),
// no P LDS bounce, 1 barrier/tile. K A-frags global->reg (off the LDS pipe).
// Only V staged in LDS (double-buffered, gl16 + pre-swizzled source).
// ws: qT 4MB | kT 4MB | vB 4MB | Op[b][n][c'] f32 8MB | Lg[b][n] 128KB | Wb 128KB

#define Bsz 8
#define Cch 256
#define CPd 64
#define Nn  4096
#define TIL 64                 // qkv/out tile
#define QBLK 128               // flash Q rows per block (4 waves x 32)
#define KVB 64                 // flash K/V tile (m)
#define NSPL 8                 // KV split factor
#define MQUAR (Nn / NSPL)      // 512

typedef __attribute__((ext_vector_type(8))) short short8;   // 8 bf16 (MFMA A/B frag)
typedef __attribute__((ext_vector_type(4))) float f32x4;    // 16x16 C/D frag
typedef __attribute__((ext_vector_type(16))) float f32x16;  // 32x32 C/D frag
typedef __attribute__((ext_vector_type(2))) unsigned uint2v;

static constexpr float C1 = (float)(1.41421 / 16.0);  // ROOT_2/sqrt(C)
static constexpr float C2 = (float)(1.41421 / 8.0);   // ROOT_2/sqrt(C')

__device__ inline unsigned pk_trunc(float lo, float hi) { // -> bf16x2 (truncate), 1 v_perm
    return __builtin_amdgcn_perm(__float_as_uint(hi), __float_as_uint(lo), 0x07060302u);
}
__device__ __forceinline__ void gl16(const unsigned short* g, unsigned short* s) {
    __builtin_amdgcn_global_load_lds(
        (const __attribute__((address_space(1))) void*)g,
        (__attribute__((address_space(3))) void*)s, 16, 0, 0);
}

// -------------------------------------------------------- W f32->bf16 conv --
__global__ __launch_bounds__(256) void wconv_kernel(
    const float* __restrict__ Wq, const float* __restrict__ Wk,
    const float* __restrict__ Wv, const float* __restrict__ Wo,
    unsigned short* __restrict__ Wb)
{
    const int idx = (blockIdx.x * 256 + threadIdx.x) * 4;   // grid 64 -> 65536 elements
    const float* src = (idx < 16384) ? Wq : (idx < 32768) ? Wk : (idx < 49152) ? Wv : Wo;
    const float4 v = *(const float4*)(src + (idx & 16383));
    *(uint2*)(Wb + idx) = make_uint2(pk_trunc(v.x, v.y), pk_trunc(v.z, v.w));
}

// --------------------------------------------------------- QKV proj (MFMA) --
__global__ __launch_bounds__(256) void qkv_kernel(
    const float* __restrict__ x, const unsigned short* __restrict__ Wb,
    const float* __restrict__ bq, const float* __restrict__ bk, const float* __restrict__ bv,
    unsigned short* __restrict__ qT, unsigned short* __restrict__ kT,
    unsigned short* __restrict__ vB)
{
    __shared__ __align__(16) unsigned short Wlds[CPd * 264];  // [o][c] bf16, stride 264 (33 KB)
    __shared__ __align__(16) float T[TIL * 68];               // 17.4 KB

    const int b   = blockIdx.y;
    const int n0  = blockIdx.x * TIL;
    const int t   = threadIdx.x;
    const int g   = t >> 6;
    const int l15 = t & 15;
    const int l4  = (t & 63) >> 4;

    // A-frags from global x: lane row n = n0+16g+l15, k = c = 8*l4 + j + 32*ks
    const float* xb = x + (size_t)b * Cch * Nn + n0 + 16 * g + l15;
    short8 xf[8];
    #pragma unroll
    for (int ks = 0; ks < 8; ++ks) {
        float xr[8];
        #pragma unroll
        for (int j = 0; j < 8; ++j)
            xr[j] = C1 * xb[(size_t)(8 * l4 + 32 * ks + j) * Nn];
        union { unsigned u[4]; short8 s; } p;
        p.u[0] = pk_trunc(xr[0], xr[1]); p.u[1] = pk_trunc(xr[2], xr[3]);
        p.u[2] = pk_trunc(xr[4], xr[5]); p.u[3] = pk_trunc(xr[6], xr[7]);
        xf[ks] = p.s;
    }

    #pragma unroll
    for (int mat = 0; mat < 3; ++mat) {
        {   // stage W[64][256] bf16 = 2048 uint4, coalesced, 8 per thread
            const uint4* wg = (const uint4*)(Wb + mat * 16384);
            #pragma unroll
            for (int p = 0; p < 8; ++p) {
                const int idx = p * 256 + t;
                const int o = idx >> 5, cs = idx & 31;
                *(uint4*)&Wlds[o * 264 + cs * 8] = wg[idx];
            }
        }
        __syncthreads();   // W staged (also: prev mat's T reads done before next T write)

        const float* bias = (mat == 0) ? bq : (mat == 1) ? bk : bv;
        f32x4 acc[4];
        #pragma unroll
        for (int st = 0; st < 4; ++st) {
            const float bb = bias[16 * st + l15];
            acc[st] = (f32x4){bb, bb, bb, bb};
        }
        #pragma unroll
        for (int st = 0; st < 4; ++st) {
            #pragma unroll
            for (int ks = 0; ks < 8; ++ks) {
                const short8 wf = *(const short8*)&Wlds[(16 * st + l15) * 264 + 8 * l4 + 32 * ks];
                acc[st] = __builtin_amdgcn_mfma_f32_16x16x32_bf16(xf[ks], wf, acc[st], 0, 0, 0);
            }
        }
        __syncthreads();   // all Wlds reads done (next mat may restage)

        if (mat < 2) {     // T as [n][c']
            #pragma unroll
            for (int st = 0; st < 4; ++st)
                #pragma unroll
                for (int r = 0; r < 4; ++r)
                    T[(16 * g + 4 * l4 + r) * 68 + 16 * st + l15] = acc[st][r];
        } else {           // v: T as [c'][n]
            #pragma unroll
            for (int st = 0; st < 4; ++st)
                #pragma unroll
                for (int r = 0; r < 4; ++r)
                    T[(16 * st + l15) * 68 + 16 * g + 4 * l4 + r] = acc[st][r];
        }
        __syncthreads();

        const int row = t >> 2;            // n (q/k) or c' (v)
        const int sg  = 16 * (t & 3);
        const float4 a0 = *(const float4*)&T[row * 68 + sg + 0];
        const float4 a1 = *(const float4*)&T[row * 68 + sg + 4];
        const float4 a2 = *(const float4*)&T[row * 68 + sg + 8];
        const float4 a3 = *(const float4*)&T[row * 68 + sg + 12];
        const uint4 lo = make_uint4(pk_trunc(a0.x, a0.y), pk_trunc(a0.z, a0.w),
                                    pk_trunc(a1.x, a1.y), pk_trunc(a1.z, a1.w));
        const uint4 hi = make_uint4(pk_trunc(a2.x, a2.y), pk_trunc(a2.z, a2.w),
                                    pk_trunc(a3.x, a3.y), pk_trunc(a3.z, a3.w));
        unsigned short* dst;
        if (mat < 2) {
            dst = (mat == 0 ? qT : kT) + ((size_t)(b * Nn + n0 + row)) * CPd + sg;
        } else {
            dst = vB + ((size_t)(b * CPd + row)) * Nn + n0 + sg;
        }
        *(uint4*)dst = lo;
        *(uint4*)(dst + 8) = hi;
    }
}

// ------------------------------------------------------------ flash (MFMA) --
// 4 waves x 32 Q-rows = 128-row Q block. Per tile (KVB=64 m):
//   - K A-frags global->reg (lane row=m, 16B contiguous along c')
//   - S^T = mfma_32x32x16(K, Q): lane holds 32 m-values (2 mh quadrants) for
//     its n = l&31 -> exp + pair-pack + permlane32_swap build PV A-frags
//     entirely in-register (no P LDS, no extra barrier)
//   - V in LDS [c'][m], gl16-staged with pre-swizzled source (chunk ^= row&7),
//     double-buffered; PV B-frags read with matching XOR
// O/L accumulated into single global buffers via atomicAdd (memset-zeroed).
__global__ __launch_bounds__(256, 3) void flash_kernel(
    const unsigned short* __restrict__ qT, const unsigned short* __restrict__ kT,
    const unsigned short* __restrict__ vB, float* __restrict__ Op, float* __restrict__ Lg)
{
    __shared__ __align__(16) unsigned short Vs[2][KVB * KVB];  // 2 x 8 KB

    const int b   = blockIdx.y;
    const int n0  = blockIdx.x * QBLK;
    const int s   = blockIdx.z;
    const int t   = threadIdx.x;
    const int l   = t & 63;
    const int g   = t >> 6;          // wave id = n-strip
    const int l31 = l & 31;
    const int hi  = l >> 5;

    // Q B-frags: Q[n = n0+32g+l31][c' = 16ks + 8hi + j]
    const unsigned short* qp = qT + ((size_t)(b * Nn + n0 + 32 * g + l31)) * CPd + 8 * hi;
    short8 qf[4];
    #pragma unroll
    for (int ks = 0; ks < 4; ++ks) qf[ks] = *(const short8*)(qp + 16 * ks);

    // V staging geometry: thread t covers phys chunk (row=t>>3 [+32], chunk=t&7);
    // source chunk = (t&7) ^ (row&7)  (row&7 identical for row and row+32)
    const int vrow = t >> 3;
    const unsigned short* vSrc = vB + (size_t)b * CPd * Nn + (size_t)vrow * Nn
                               + 8 * ((t & 7) ^ (vrow & 7));
    const unsigned short* vSrc2 = vSrc + (size_t)32 * Nn;

    const unsigned short* kB = kT + (size_t)b * Nn * CPd;
    const int mbase = s * MQUAR;

    f32x16 acco[2];
    #pragma unroll
    for (int ch = 0; ch < 2; ++ch)
        #pragma unroll
        for (int i = 0; i < 16; ++i) acco[ch][i] = 0.f;
    float Lacc = 0.f;

    {   // prologue: stage tile 0 into buf 0
        unsigned short* dst = &Vs[0][t * 8];
        gl16(vSrc + mbase, dst);
        gl16(vSrc2 + mbase, dst + 2048);
    }

    const int nt = MQUAR / KVB;   // 8
    for (int ti = 0; ti < nt; ++ti) {
        const int m0 = mbase + ti * KVB;

        // K A-frags for this tile (issue before barrier to overlap latency)
        short8 kf[2][4];
        #pragma unroll
        for (int mh = 0; mh < 2; ++mh) {
            const unsigned short* kp = kB + (size_t)(m0 + 32 * mh + l31) * CPd + 8 * hi;
            #pragma unroll
            for (int ks = 0; ks < 4; ++ks) kf[mh][ks] = *(const short8*)(kp + 16 * ks);
        }

        __syncthreads();   // all waves done PV(ti-1); vmcnt(0) -> V(ti) visible

        if (ti + 1 < nt) {   // stage next tile into the other buffer
            unsigned short* dst = &Vs[(ti + 1) & 1][t * 8];
            gl16(vSrc + m0 + KVB, dst);
            gl16(vSrc2 + m0 + KVB, dst + 2048);
        }

        // ---- S^T = K Q^T : acc[mh][reg] = S[n=l31][m = (reg&3)+8*(reg>>2)+4hi+32mh]
        f32x16 accs[2];
        #pragma unroll
        for (int mh = 0; mh < 2; ++mh) {
            #pragma unroll
            for (int i = 0; i < 16; ++i) accs[mh][i] = 0.f;
            #pragma unroll
            for (int ks = 0; ks < 4; ++ks)
                accs[mh] = __builtin_amdgcn_mfma_f32_32x32x16_bf16(kf[mh][ks], qf[ks],
                                                                   accs[mh], 0, 0, 0);
        }

        // ---- P = exp(S^T); in-register pack to PV A-frags (T12) ----
        short8 pa[4];
        #pragma unroll
        for (int mh = 0; mh < 2; ++mh) {
            float p[16];
            #pragma unroll
            for (int r = 0; r < 16; ++r) {
                p[r] = __expf(accs[mh][r]);
                Lacc += p[r];
            }
            unsigned uA[4], uB[4];
            #pragma unroll
            for (int q = 0; q < 4; ++q) {
                uA[q] = pk_trunc(p[4 * q + 0], p[4 * q + 1]);   // m = 8q+4hi+32mh+{0,1}
                uB[q] = pk_trunc(p[4 * q + 2], p[4 * q + 3]);   // m = 8q+4hi+32mh+{2,3}
            }
            #pragma unroll
            for (int k2 = 0; k2 < 2; ++k2) {
                // swap(uX[2k2], uX[2k2+1]): [0] = frag word j{0,1}, [1] = word j{4,5}
                uint2v wa = __builtin_amdgcn_permlane32_swap(uA[2 * k2], uA[2 * k2 + 1],
                                                             false, false);
                uint2v wb = __builtin_amdgcn_permlane32_swap(uB[2 * k2], uB[2 * k2 + 1],
                                                             false, false);
                union { unsigned u[4]; short8 s; } w;
                w.u[0] = wa[0]; w.u[1] = wb[0]; w.u[2] = wa[1]; w.u[3] = wb[1];
                pa[2 * mh + k2] = w.s;   // A-frag for m in [16*(2mh+k2), +16)
            }
        }

        // ---- O += P V^T : B-frag V[c'=32ch+l31][m=16ks+8hi+j], XOR-swizzled ----
        const unsigned short* Vr = Vs[ti & 1];
        #pragma unroll
        for (int ks = 0; ks < 4; ++ks) {
            #pragma unroll
            for (int ch = 0; ch < 2; ++ch) {
                const int row  = 32 * ch + l31;
                const int phys = (2 * ks + hi) ^ (l & 7);
                const short8 vf = *(const short8*)&Vr[row * KVB + 8 * phys];
                acco[ch] = __builtin_amdgcn_mfma_f32_32x32x16_bf16(pa[ks], vf,
                                                                   acco[ch], 0, 0, 0);
            }
        }
    }

    // ---- epilogue: L reduce across hi halves; atomic-accumulate O and L ----
    const float Ltot = Lacc + __shfl_xor(Lacc, 32, 64);
    if (hi == 0)
        atomicAdd(&Lg[(size_t)b * Nn + n0 + 32 * g + l31], Ltot);

    float* ob = Op + ((size_t)(b * Nn + n0 + 32 * g)) * CPd;
    #pragma unroll
    for (int r = 0; r < 16; ++r) {
        const int nl = (r & 3) + 8 * (r >> 2) + 4 * hi;
        #pragma unroll
        for (int ch = 0; ch < 2; ++ch)
            atomicAdd(&ob[(size_t)nl * CPd + 32 * ch + l31], acco[ch][r]);
    }
}

// ------------------------------------------------------- output proj (MFMA) --
__global__ __launch_bounds__(512) void out_kernel(
    const float* __restrict__ Op, const float* __restrict__ Lg,
    const unsigned short* __restrict__ Wob,
    const float* __restrict__ bo, const float* __restrict__ gamma,
    const float* __restrict__ x, float* __restrict__ y)
{
    __shared__ __align__(16) unsigned short Wos[Cch * 72];  // 36 KB
    __shared__ __align__(16) unsigned short Sas[TIL * 72];  // 9 KB
    __shared__ float bos[Cch];

    const int b   = blockIdx.y;
    const int n0  = blockIdx.x * TIL;
    const int t   = threadIdx.x;     // 0..511
    const int l   = t & 63;
    const int w   = t >> 6;          // 8 waves
    const int l15 = l & 15;
    const int l4  = l >> 4;

    if (t < Cch) bos[t] = bo[t];
    {   // Wo bf16: 2048 uint4 / 512 threads = 4 each
        const uint4* wg = (const uint4*)Wob;
        #pragma unroll
        for (int p = 0; p < 4; ++p) {
            const int idx = p * 512 + t;
            const int row = idx >> 3, seg = idx & 7;
            *(uint4*)&Wos[row * 72 + seg * 8] = wg[idx];
        }
    }
    if (t < 256) {   // normalize accumulated partials + pack sa tile to bf16
        const int n = t >> 2, seg = t & 3;
        const float* o0 = Op + ((size_t)(b * Nn + n0 + n)) * CPd + seg * 16;
        const float sc = C2 / Lg[(size_t)b * Nn + n0 + n];
        unsigned pk[8];
        #pragma unroll
        for (int i = 0; i < 4; ++i) {
            const float4 a = ((const float4*)o0)[i];
            pk[2 * i]     = pk_trunc(a.x * sc, a.y * sc);
            pk[2 * i + 1] = pk_trunc(a.z * sc, a.w * sc);
        }
        *(uint4*)&Sas[n * 72 + seg * 16]     = make_uint4(pk[0], pk[1], pk[2], pk[3]);
        *(uint4*)&Sas[n * 72 + seg * 16 + 8] = make_uint4(pk[4], pk[5], pk[6], pk[7]);
    }
    __syncthreads();

    short8 bfr[4][2];
    #pragma unroll
    for (int ns = 0; ns < 4; ++ns) {
        bfr[ns][0] = *(const short8*)&Sas[(16 * ns + l15) * 72 + 8 * l4];
        bfr[ns][1] = *(const short8*)&Sas[(16 * ns + l15) * 72 + 8 * l4 + 32];
    }
    const float gam = gamma[0];
    const float* xb = x + (size_t)b * Cch * Nn;
    float*       yb = y + (size_t)b * Cch * Nn;

    #pragma unroll
    for (int os2 = 0; os2 < 2; ++os2) {
        const int obase = 16 * (w + 8 * os2);     // 16 strips over 8 waves x 2
        const short8 af0 = *(const short8*)&Wos[(obase + l15) * 72 + 8 * l4];
        const short8 af1 = *(const short8*)&Wos[(obase + l15) * 72 + 8 * l4 + 32];
        #pragma unroll
        for (int ns = 0; ns < 4; ++ns) {
            f32x4 acc = (f32x4){0.f, 0.f, 0.f, 0.f};
            acc = __builtin_amdgcn_mfma_f32_16x16x32_bf16(af0, bfr[ns][0], acc, 0, 0, 0);
            acc = __builtin_amdgcn_mfma_f32_16x16x32_bf16(af1, bfr[ns][1], acc, 0, 0, 0);
            #pragma unroll
            for (int r = 0; r < 4; ++r) {
                const int o = obase + 4 * l4 + r;
                const size_t idx = (size_t)o * Nn + n0 + 16 * ns + l15;
                yb[idx] = fmaf(gam, acc[r] + bos[o], xb[idx]);
            }
        }
    }
}

// ---------------------------------------------------------------------------
extern "C" void kernel_launch(void* const* d_in, const int* in_sizes, int n_in,
                              void* d_out, int out_size, void* d_ws, size_t ws_size,
                              hipStream_t stream)
{
    (void)in_sizes; (void)n_in; (void)out_size; (void)ws_size;
    const float* x     = (const float*)d_in[0];
    const float* Wq    = (const float*)d_in[1];
    const float* bq    = (const float*)d_in[2];
    const float* Wk    = (const float*)d_in[3];
    const float* bk    = (const float*)d_in[4];
    const float* Wv    = (const float*)d_in[5];
    const float* bv    = (const float*)d_in[6];
    const float* Wo    = (const float*)d_in[7];
    const float* bo    = (const float*)d_in[8];
    const float* gamma = (const float*)d_in[9];
    float* y = (float*)d_out;

    const size_t per = (size_t)Bsz * Nn * CPd;           // 2,097,152 elements
    unsigned short* qT = (unsigned short*)d_ws;          // 4 MB
    unsigned short* kT = qT + per;                       // 4 MB
    unsigned short* vB = kT + per;                       // 4 MB
    float* Op = (float*)(vB + per);                      // 8 MB: [b][n][c'] f32 accum
    float* Lg = Op + per;                                // 128 KB: [b][n] f32 accum
    unsigned short* Wb = (unsigned short*)(Lg + (size_t)Bsz * Nn);  // 128 KB

    // zero the atomically-accumulated partials (Op + Lg are contiguous)
    hipMemsetAsync(Op, 0, (per + (size_t)Bsz * Nn) * sizeof(float), stream);

    dim3 grid(Nn / TIL, Bsz);
    dim3 gridF(Nn / QBLK, Bsz, NSPL);
    wconv_kernel<<<64, 256, 0, stream>>>(Wq, Wk, Wv, Wo, Wb);
    qkv_kernel<<<grid, 256, 0, stream>>>(x, Wb, bq, bk, bv, qT, kT, vB);
    flash_kernel<<<gridF, 256, 0, stream>>>(qT, kT, vB, Op, Lg);
    out_kernel<<<grid, 512, 0, stream>>>(Op, Lg, Wb + 3 * 16384, bo, gamma, x, y);
}

// Round 3
// 197.552 us; speedup vs baseline: 1.0439x; 1.0439x over previous
//
#include <hip/hip_runtime.h>

// Non-local (SAGAN) block on MI355X. B=8, C=256, C'=64, N=4096.
// Round 9: flash reverted to the proven R7 structure (82us). New focus: the
// ~108us OUTSIDE flash. qkv: 512-thr 8-wave blocks (o-strips split across
// wave pairs) -> 24 waves/CU (was 8). out: grid.z=2 o-halves, 27.5KB LDS,
// per-ns frag loads (VGPR<=64) -> 32 waves/CU, half work per block.
// ws: qT 4MB | kT 4MB | vB 4MB | Op[b][n][c'] f32 8MB | Lg[b][n] 128KB | Wb 128KB

#define Bsz 8
#define Cch 256
#define CPd 64
#define Nn  4096
#define TIL 64
#define NSPL 4                 // KV split factor
#define MQUAR (Nn / NSPL)      // 1024

typedef __attribute__((ext_vector_type(8))) short short8;   // 8 bf16 (MFMA A/B frag)
typedef __attribute__((ext_vector_type(4))) float f32x4;    // 16x16 C/D frag

static constexpr float C1 = (float)(1.41421 / 16.0);  // ROOT_2/sqrt(C)
static constexpr float C2 = (float)(1.41421 / 8.0);   // ROOT_2/sqrt(C')

__device__ inline unsigned pk_trunc(float lo, float hi) { // -> bf16x2 (truncate), 1 v_perm
    return __builtin_amdgcn_perm(__float_as_uint(hi), __float_as_uint(lo), 0x07060302u);
}
__device__ inline float dpp_swap1(float v) {  // lane l <-> l^1 (quad_perm [1,0,3,2])
    return __uint_as_float((unsigned)__builtin_amdgcn_mov_dpp(
        (int)__float_as_uint(v), 0xB1, 0xF, 0xF, true));
}
__device__ __forceinline__ void gl16(const unsigned short* g, unsigned short* s) {
    __builtin_amdgcn_global_load_lds(
        (const __attribute__((address_space(1))) void*)g,
        (__attribute__((address_space(3))) void*)s, 16, 0, 0);
}

// -------------------------------------------------------- W f32->bf16 conv --
__global__ __launch_bounds__(256) void wconv_kernel(
    const float* __restrict__ Wq, const float* __restrict__ Wk,
    const float* __restrict__ Wv, const float* __restrict__ Wo,
    unsigned short* __restrict__ Wb)
{
    const int idx = (blockIdx.x * 256 + threadIdx.x) * 4;   // grid 64 -> 65536 elements
    const float* src = (idx < 16384) ? Wq : (idx < 32768) ? Wk : (idx < 49152) ? Wv : Wo;
    const float4 v = *(const float4*)(src + (idx & 16383));
    *(uint2*)(Wb + idx) = make_uint2(pk_trunc(v.x, v.y), pk_trunc(v.z, v.w));
}

// --------------------------------------------------------- QKV proj (MFMA) --
// 512 threads / 8 waves. Wave g: n-strip = g&3, o-half = g>>2 (2 o-strips of
// 16). Each wave: 16 MFMA (was 32 with 4 waves) -> 2x latency hiding at same
// traffic. 3 blocks/CU (50.4KB LDS) = 24 waves/CU.
__global__ __launch_bounds__(512, 4) void qkv_kernel(
    const float* __restrict__ x, const unsigned short* __restrict__ Wb,
    const float* __restrict__ bq, const float* __restrict__ bk, const float* __restrict__ bv,
    unsigned short* __restrict__ qT, unsigned short* __restrict__ kT,
    unsigned short* __restrict__ vB)
{
    __shared__ __align__(16) unsigned short Wlds[CPd * 264];  // [o][c] bf16 (33 KB)
    __shared__ __align__(16) float T[TIL * 68];               // 17.4 KB

    const int b   = blockIdx.y;
    const int n0  = blockIdx.x * TIL;
    const int t   = threadIdx.x;       // 0..511
    const int g   = t >> 6;            // wave 0..7
    const int ns_ = g & 3;             // n-strip (16 rows)
    const int oh  = g >> 2;            // o-half (st pair)
    const int l15 = t & 15;
    const int l4  = (t & 63) >> 4;

    // A-frags from global x: lane row n = n0+16ns_+l15, k = c = 8*l4 + j + 32*ks
    const float* xb = x + (size_t)b * Cch * Nn + n0 + 16 * ns_ + l15;
    short8 xf[8];
    #pragma unroll
    for (int ks = 0; ks < 8; ++ks) {
        float xr[8];
        #pragma unroll
        for (int j = 0; j < 8; ++j)
            xr[j] = C1 * xb[(size_t)(8 * l4 + 32 * ks + j) * Nn];
        union { unsigned u[4]; short8 s; } p;
        p.u[0] = pk_trunc(xr[0], xr[1]); p.u[1] = pk_trunc(xr[2], xr[3]);
        p.u[2] = pk_trunc(xr[4], xr[5]); p.u[3] = pk_trunc(xr[6], xr[7]);
        xf[ks] = p.s;
    }

    #pragma unroll
    for (int mat = 0; mat < 3; ++mat) {
        {   // stage W[64][256] bf16 = 2048 uint4, coalesced, 4 per thread
            const uint4* wg = (const uint4*)(Wb + mat * 16384);
            #pragma unroll
            for (int p = 0; p < 4; ++p) {
                const int idx = p * 512 + t;
                const int o = idx >> 5, cs = idx & 31;
                *(uint4*)&Wlds[o * 264 + cs * 8] = wg[idx];
            }
        }
        __syncthreads();   // W staged

        const float* bias = (mat == 0) ? bq : (mat == 1) ? bk : bv;
        f32x4 acc[2];
        #pragma unroll
        for (int i = 0; i < 2; ++i) {
            const float bb = bias[16 * (2 * oh + i) + l15];
            acc[i] = (f32x4){bb, bb, bb, bb};
        }
        #pragma unroll
        for (int i = 0; i < 2; ++i) {
            const int st = 2 * oh + i;
            #pragma unroll
            for (int ks = 0; ks < 8; ++ks) {
                const short8 wf = *(const short8*)&Wlds[(16 * st + l15) * 264 + 8 * l4 + 32 * ks];
                acc[i] = __builtin_amdgcn_mfma_f32_16x16x32_bf16(xf[ks], wf, acc[i], 0, 0, 0);
            }
        }
        __syncthreads();   // all Wlds reads done (next mat restages)

        if (mat < 2) {     // T as [n][c']
            #pragma unroll
            for (int i = 0; i < 2; ++i)
                #pragma unroll
                for (int r = 0; r < 4; ++r)
                    T[(16 * ns_ + 4 * l4 + r) * 68 + 16 * (2 * oh + i) + l15] = acc[i][r];
        } else {           // v: T as [c'][n]
            #pragma unroll
            for (int i = 0; i < 2; ++i)
                #pragma unroll
                for (int r = 0; r < 4; ++r)
                    T[(16 * (2 * oh + i) + l15) * 68 + 16 * ns_ + 4 * l4 + r] = acc[i][r];
        }
        __syncthreads();

        // pack + store: 64x64 f32 -> bf16, 1 uint4 per thread (full 128B lines)
        const int row = t >> 3;            // n (q/k) or c' (v)
        const int sg  = 8 * (t & 7);
        const float4 a0 = *(const float4*)&T[row * 68 + sg + 0];
        const float4 a1 = *(const float4*)&T[row * 68 + sg + 4];
        const uint4 o4 = make_uint4(pk_trunc(a0.x, a0.y), pk_trunc(a0.z, a0.w),
                                    pk_trunc(a1.x, a1.y), pk_trunc(a1.z, a1.w));
        unsigned short* dst;
        if (mat < 2) {
            dst = (mat == 0 ? qT : kT) + ((size_t)(b * Nn + n0 + row)) * CPd + sg;
        } else {
            dst = vB + ((size_t)(b * CPd + row)) * Nn + n0 + sg;
        }
        *(uint4*)dst = o4;
        // no barrier needed here: next T write is ordered behind two syncs
    }
}

// ------------------------------------------------------------ flash (MFMA) --
// R7 structure (proven 82us): NSPL=4, 6 blocks/CU. K/V tiles: linear [64][64]
// bf16 in LDS, staged by global_load_lds with pre-swizzled global source:
// LDS[row][chunk] = G[row][chunk ^ (row&7)] (chunk = 16B). Reads apply the
// same XOR. Partial O and L accumulated into single global buffers (atomics).
__global__ __launch_bounds__(256, 6) void flash_kernel(
    const unsigned short* __restrict__ qT, const unsigned short* __restrict__ kT,
    const unsigned short* __restrict__ vB, float* __restrict__ Op, float* __restrict__ Lg)
{
    __shared__ __align__(16) unsigned short Ks[TIL * 64];  // [m][c'] swizzled, 8 KB
    __shared__ __align__(16) unsigned short Vs[TIL * 64];  // [c'][m] swizzled, 8 KB
    __shared__ __align__(16) unsigned Pb[TIL * 34];        // bf16-pair [n][m/2], 8.7 KB
    __shared__ float Lsh[TIL];

    const int b   = blockIdx.y;
    const int n0  = blockIdx.x * TIL;
    const int s   = blockIdx.z;
    const int t   = threadIdx.x;
    const int l   = t & 63;
    const int g   = t >> 6;
    const int l15 = l & 15;
    const int l4  = l >> 4;
    const int par = l & 1;
    const unsigned sel = par ? 0x03020706u : 0x07060302u;
    const int l15h = l15 >> 1;

    if (t < TIL) Lsh[t] = 0.f;

    // Q A-frags straight from global
    const unsigned short* qp = qT + (size_t)(b * Nn + n0 + 16 * g + l15) * CPd + 8 * l4;
    const short8 qf0 = *(const short8*)qp;
    const short8 qf1 = *(const short8*)(qp + 32);

    f32x4 acco[4];
    #pragma unroll
    for (int ct = 0; ct < 4; ++ct) acco[ct] = (f32x4){0.f, 0.f, 0.f, 0.f};
    float Lp[4] = {0.f, 0.f, 0.f, 0.f};

    // staging geometry: wave g stages rows [16g,16g+16); lane covers
    // row 16g + (l>>3) (+8 on 2nd op), LDS chunk l&7 <- source chunk (l&7)^(row&7)
    const int r16 = (l >> 3) & 7;
    const int sch = (l & 7) ^ r16;
    const unsigned short* kSrc = kT + (size_t)b * Nn * CPd
                               + (size_t)(16 * g + r16) * CPd + sch * 8;
    const unsigned short* vSrc = vB + (size_t)b * CPd * Nn
                               + (size_t)(16 * g + r16) * Nn + sch * 8;
    unsigned short* KsW = &Ks[(16 * g) * 64];
    unsigned short* VsW = &Vs[(16 * g) * 64];

    // read-side swizzle: chunk c at row r lives at chunk c^(r&7)
    const int h7  = l15 & 7;
    const int sw0 = (l4 ^ h7) << 4;               // byte offset of chunk, ks=0 (ks=1: ^64)
    const char* KsB = (const char*)Ks + (l15 << 7);
    const char* VsB = (const char*)Vs + (l15 << 7);

    const int mbase = s * MQUAR;
    for (int mi = 0; mi < MQUAR; mi += TIL) {
        const int m0 = mbase + mi;
        __syncthreads();   // prev tile's LDS reads done
        gl16(kSrc + (size_t)m0 * CPd,       KsW);            // K rows 16g..16g+7
        gl16(kSrc + (size_t)(m0 + 8) * CPd, KsW + 8 * 64);   // K rows 16g+8..16g+15
        gl16(vSrc + m0,                     VsW);            // V rows (c') 16g..16g+7
        gl16(vSrc + (size_t)8 * Nn + m0,    VsW + 8 * 64);   // V rows 16g+8..16g+15
        __syncthreads();   // staged (barrier drains vmcnt)

        // ---- S = Q^T K: 4 independent chains x 2 k-steps ----
        f32x4 accs[4];
        #pragma unroll
        for (int st = 0; st < 4; ++st) {
            accs[st] = (f32x4){0.f, 0.f, 0.f, 0.f};
            const short8 kf0 = *(const short8*)(KsB + (st << 11) + sw0);
            const short8 kf1 = *(const short8*)(KsB + (st << 11) + (sw0 ^ 64));
            accs[st] = __builtin_amdgcn_mfma_f32_16x16x32_bf16(qf0, kf0, accs[st], 0, 0, 0);
            accs[st] = __builtin_amdgcn_mfma_f32_16x16x32_bf16(qf1, kf1, accs[st], 0, 0, 0);
        }

        // ---- P = exp(S); DPP pair-pack to bf16; write half the rows per parity ----
        #pragma unroll
        for (int st = 0; st < 4; ++st) {
            unsigned u[4];
            #pragma unroll
            for (int r = 0; r < 4; ++r) {
                float p = __expf(accs[st][r]);
                Lp[r] += p;
                float nb = dpp_swap1(p);
                u[r] = __builtin_amdgcn_perm(__float_as_uint(nb), __float_as_uint(p), sel);
            }
            const int rb = 16 * g + 4 * l4 + 2 * par;   // even lane: rows {0,1}; odd: {2,3}
            Pb[(rb + 0) * 34 + 8 * st + l15h] = u[2 * par];
            Pb[(rb + 1) * 34 + 8 * st + l15h] = u[2 * par + 1];
        }
        __syncthreads();   // P visible

        // ---- O += P V^T: A-frag from Pb (pre-packed bf16), B-frag V ----
        #pragma unroll
        for (int ks = 0; ks < 2; ++ks) {
            const short8 pf = *(const short8*)&Pb[(16 * g + l15) * 34 + 4 * l4 + 16 * ks];
            const int swk = sw0 ^ (ks << 6);
            #pragma unroll
            for (int ct = 0; ct < 4; ++ct) {
                const short8 vf = *(const short8*)(VsB + (ct << 11) + swk);
                acco[ct] = __builtin_amdgcn_mfma_f32_16x16x32_bf16(pf, vf, acco[ct], 0, 0, 0);
            }
        }
    }

    #pragma unroll
    for (int r = 0; r < 4; ++r) atomicAdd(&Lsh[16 * g + 4 * l4 + r], Lp[r]);
    __syncthreads();

    float* ob = Op + ((size_t)(b * Nn + n0)) * CPd;
    #pragma unroll
    for (int r = 0; r < 4; ++r) {
        const int nl = 16 * g + 4 * l4 + r;
        #pragma unroll
        for (int ct = 0; ct < 4; ++ct)
            atomicAdd(&ob[(size_t)nl * CPd + 16 * ct + l15], acco[ct][r]);
    }
    if (t < TIL) atomicAdd(&Lg[(size_t)b * Nn + n0 + t], Lsh[t]);
}

// ------------------------------------------------------- output proj (MFMA) --
// grid.z=2 splits the 256 o rows: each block stages half of Wo (18KB) and
// computes 128o x 64n. 27.5KB LDS, 1 strip/wave, per-ns frag loads -> low
// VGPR -> 4 blocks/CU x 8 waves = 32 waves/CU.
__global__ __launch_bounds__(512, 8) void out_kernel(
    const float* __restrict__ Op, const float* __restrict__ Lg,
    const unsigned short* __restrict__ Wob,
    const float* __restrict__ bo, const float* __restrict__ gamma,
    const float* __restrict__ x, float* __restrict__ y)
{
    __shared__ __align__(16) unsigned short Wos[128 * 72];  // 18 KB (half of Wo)
    __shared__ __align__(16) unsigned short Sas[TIL * 72];  // 9 KB
    __shared__ float bos[128];

    const int b   = blockIdx.y;
    const int n0  = blockIdx.x * TIL;
    const int oz  = blockIdx.z;      // o-half
    const int t   = threadIdx.x;     // 0..511
    const int l   = t & 63;
    const int w   = t >> 6;          // 8 waves -> 8 o-strips of 16
    const int l15 = l & 15;
    const int l4  = l >> 4;

    if (t < 128) bos[t] = bo[128 * oz + t];
    {   // half Wo bf16: 1024 uint4 / 512 threads = 2 each
        const uint4* wg = (const uint4*)Wob + 1024 * oz;
        #pragma unroll
        for (int p = 0; p < 2; ++p) {
            const int idx = p * 512 + t;
            const int row = idx >> 3, seg = idx & 7;
            *(uint4*)&Wos[row * 72 + seg * 8] = wg[idx];
        }
    }
    if (t < 256) {   // normalize accumulated partials + pack sa tile to bf16
        const int n = t >> 2, seg = t & 3;
        const float* o0 = Op + ((size_t)(b * Nn + n0 + n)) * CPd + seg * 16;
        const float sc = C2 / Lg[(size_t)b * Nn + n0 + n];
        unsigned pk[8];
        #pragma unroll
        for (int i = 0; i < 4; ++i) {
            const float4 a = ((const float4*)o0)[i];
            pk[2 * i]     = pk_trunc(a.x * sc, a.y * sc);
            pk[2 * i + 1] = pk_trunc(a.z * sc, a.w * sc);
        }
        *(uint4*)&Sas[n * 72 + seg * 16]     = make_uint4(pk[0], pk[1], pk[2], pk[3]);
        *(uint4*)&Sas[n * 72 + seg * 16 + 8] = make_uint4(pk[4], pk[5], pk[6], pk[7]);
    }
    __syncthreads();

    const float gam = gamma[0];
    const float* xb = x + (size_t)(b * Cch + 128 * oz) * Nn;
    float*       yb = y + (size_t)(b * Cch + 128 * oz) * Nn;

    const int obase = 16 * w;        // local o-strip
    const short8 af0 = *(const short8*)&Wos[(obase + l15) * 72 + 8 * l4];
    const short8 af1 = *(const short8*)&Wos[(obase + l15) * 72 + 8 * l4 + 32];
    #pragma unroll
    for (int ns = 0; ns < 4; ++ns) {
        const short8 b0 = *(const short8*)&Sas[(16 * ns + l15) * 72 + 8 * l4];
        const short8 b1 = *(const short8*)&Sas[(16 * ns + l15) * 72 + 8 * l4 + 32];
        f32x4 acc = (f32x4){0.f, 0.f, 0.f, 0.f};
        acc = __builtin_amdgcn_mfma_f32_16x16x32_bf16(af0, b0, acc, 0, 0, 0);
        acc = __builtin_amdgcn_mfma_f32_16x16x32_bf16(af1, b1, acc, 0, 0, 0);
        #pragma unroll
        for (int r = 0; r < 4; ++r) {
            const int ol = obase + 4 * l4 + r;           // local o (0..127)
            const size_t idx = (size_t)ol * Nn + n0 + 16 * ns + l15;
            yb[idx] = fmaf(gam, acc[r] + bos[ol], xb[idx]);
        }
    }
}

// ---------------------------------------------------------------------------
extern "C" void kernel_launch(void* const* d_in, const int* in_sizes, int n_in,
                              void* d_out, int out_size, void* d_ws, size_t ws_size,
                              hipStream_t stream)
{
    (void)in_sizes; (void)n_in; (void)out_size; (void)ws_size;
    const float* x     = (const float*)d_in[0];
    const float* Wq    = (const float*)d_in[1];
    const float* bq    = (const float*)d_in[2];
    const float* Wk    = (const float*)d_in[3];
    const float* bk    = (const float*)d_in[4];
    const float* Wv    = (const float*)d_in[5];
    const float* bv    = (const float*)d_in[6];
    const float* Wo    = (const float*)d_in[7];
    const float* bo    = (const float*)d_in[8];
    const float* gamma = (const float*)d_in[9];
    float* y = (float*)d_out;

    const size_t per = (size_t)Bsz * Nn * CPd;           // 2,097,152 elements
    unsigned short* qT = (unsigned short*)d_ws;          // 4 MB
    unsigned short* kT = qT + per;                       // 4 MB
    unsigned short* vB = kT + per;                       // 4 MB
    float* Op = (float*)(vB + per);                      // 8 MB: [b][n][c'] f32 accum
    float* Lg = Op + per;                                // 128 KB: [b][n] f32 accum
    unsigned short* Wb = (unsigned short*)(Lg + (size_t)Bsz * Nn);  // 128 KB

    // zero the atomically-accumulated partials (Op + Lg are contiguous)
    hipMemsetAsync(Op, 0, (per + (size_t)Bsz * Nn) * sizeof(float), stream);

    dim3 grid(Nn / TIL, Bsz);
    dim3 gridO(Nn / TIL, Bsz, 2);
    dim3 gridF(Nn / TIL, Bsz, NSPL);
    wconv_kernel<<<64, 256, 0, stream>>>(Wq, Wk, Wv, Wo, Wb);
    qkv_kernel<<<grid, 512, 0, stream>>>(x, Wb, bq, bk, bv, qT, kT, vB);
    flash_kernel<<<gridF, 256, 0, stream>>>(qT, kT, vB, Op, Lg);
    out_kernel<<<gridO, 512, 0, stream>>>(Op, Lg, Wb + 3 * 16384, bo, gamma, x, y);
}

// Round 5
// 190.568 us; speedup vs baseline: 1.0822x; 1.0366x over previous
//
#include <hip/hip_runtime.h>

// Non-local (SAGAN) block on MI355X. B=8, C=256, C'=64, N=4096.
// Round 11 (= R10 resubmit, inline-asm exp removed): qkv/out are R7-exact.
// Flash: 512-thr/128-row blocks, K/V double-buffered in 4 statically-named
// LDS arrays (stage issued before compute, 1 __syncthreads per tile),
// P-barrier removed (P is wave-private), exp2 trick (log2e folded into
// Wq/bq -> native exp2f), shuffle-L epilogue.
// ws: qT 4MB | kT 4MB | vB 4MB | Op[b][n][c'] f32 8MB | Lg[b][n] 128KB | Wb 128KB

#define Bsz 8
#define Cch 256
#define CPd 64
#define Nn  4096
#define TIL 64
#define QROWS 128              // flash Q rows per block (8 waves x 16)
#define NSPL 4                 // KV split factor
#define MQUAR (Nn / NSPL)      // 1024

typedef __attribute__((ext_vector_type(8))) short short8;   // 8 bf16 (MFMA A/B frag)
typedef __attribute__((ext_vector_type(4))) float f32x4;    // 16x16 C/D frag

static constexpr float C1 = (float)(1.41421 / 16.0);  // ROOT_2/sqrt(C)
static constexpr float C2 = (float)(1.41421 / 8.0);   // ROOT_2/sqrt(C')
static constexpr float LOG2E = 1.44269504f;

__device__ inline unsigned pk_trunc(float lo, float hi) { // -> bf16x2 (truncate), 1 v_perm
    return __builtin_amdgcn_perm(__float_as_uint(hi), __float_as_uint(lo), 0x07060302u);
}
__device__ inline float dpp_swap1(float v) {  // lane l <-> l^1 (quad_perm [1,0,3,2])
    return __uint_as_float((unsigned)__builtin_amdgcn_mov_dpp(
        (int)__float_as_uint(v), 0xB1, 0xF, 0xF, true));
}
__device__ __forceinline__ void gl16(const unsigned short* g, unsigned short* s) {
    __builtin_amdgcn_global_load_lds(
        (const __attribute__((address_space(1))) void*)g,
        (__attribute__((address_space(3))) void*)s, 16, 0, 0);
}

// -------------------------------------------------------- W f32->bf16 conv --
// Wq is pre-scaled by log2e so flash can use native exp2 (one v_exp_f32).
__global__ __launch_bounds__(256) void wconv_kernel(
    const float* __restrict__ Wq, const float* __restrict__ Wk,
    const float* __restrict__ Wv, const float* __restrict__ Wo,
    unsigned short* __restrict__ Wb)
{
    const int idx = (blockIdx.x * 256 + threadIdx.x) * 4;   // grid 64 -> 65536 elements
    const float* src = (idx < 16384) ? Wq : (idx < 32768) ? Wk : (idx < 49152) ? Wv : Wo;
    const float sc = (idx < 16384) ? LOG2E : 1.0f;
    const float4 v = *(const float4*)(src + (idx & 16383));
    *(uint2*)(Wb + idx) = make_uint2(pk_trunc(sc * v.x, sc * v.y),
                                     pk_trunc(sc * v.z, sc * v.w));
}

// --------------------------------------------------------- QKV proj (MFMA) --
__global__ __launch_bounds__(256) void qkv_kernel(
    const float* __restrict__ x, const unsigned short* __restrict__ Wb,
    const float* __restrict__ bq, const float* __restrict__ bk, const float* __restrict__ bv,
    unsigned short* __restrict__ qT, unsigned short* __restrict__ kT,
    unsigned short* __restrict__ vB)
{
    __shared__ __align__(16) unsigned short Wlds[CPd * 264];  // [o][c] bf16 (33 KB)
    __shared__ __align__(16) float T[TIL * 68];               // 17.4 KB

    const int b   = blockIdx.y;
    const int n0  = blockIdx.x * TIL;
    const int t   = threadIdx.x;
    const int g   = t >> 6;
    const int l15 = t & 15;
    const int l4  = (t & 63) >> 4;

    // A-frags from global x: lane row n = n0+16g+l15, k = c = 8*l4 + j + 32*ks
    const float* xb = x + (size_t)b * Cch * Nn + n0 + 16 * g + l15;
    short8 xf[8];
    #pragma unroll
    for (int ks = 0; ks < 8; ++ks) {
        float xr[8];
        #pragma unroll
        for (int j = 0; j < 8; ++j)
            xr[j] = C1 * xb[(size_t)(8 * l4 + 32 * ks + j) * Nn];
        union { unsigned u[4]; short8 s; } p;
        p.u[0] = pk_trunc(xr[0], xr[1]); p.u[1] = pk_trunc(xr[2], xr[3]);
        p.u[2] = pk_trunc(xr[4], xr[5]); p.u[3] = pk_trunc(xr[6], xr[7]);
        xf[ks] = p.s;
    }

    #pragma unroll
    for (int mat = 0; mat < 3; ++mat) {
        {   // stage W[64][256] bf16 = 2048 uint4, coalesced, 8 per thread
            const uint4* wg = (const uint4*)(Wb + mat * 16384);
            #pragma unroll
            for (int p = 0; p < 8; ++p) {
                const int idx = p * 256 + t;
                const int o = idx >> 5, cs = idx & 31;
                *(uint4*)&Wlds[o * 264 + cs * 8] = wg[idx];
            }
        }
        __syncthreads();   // W staged

        const float* bias = (mat == 0) ? bq : (mat == 1) ? bk : bv;
        const float bsc = (mat == 0) ? LOG2E : 1.0f;   // match Wq's log2e scale
        f32x4 acc[4];
        #pragma unroll
        for (int st = 0; st < 4; ++st) {
            const float bb = bsc * bias[16 * st + l15];
            acc[st] = (f32x4){bb, bb, bb, bb};
        }
        #pragma unroll
        for (int st = 0; st < 4; ++st) {
            #pragma unroll
            for (int ks = 0; ks < 8; ++ks) {
                const short8 wf = *(const short8*)&Wlds[(16 * st + l15) * 264 + 8 * l4 + 32 * ks];
                acc[st] = __builtin_amdgcn_mfma_f32_16x16x32_bf16(xf[ks], wf, acc[st], 0, 0, 0);
            }
        }
        __syncthreads();   // all Wlds reads done (next mat may restage)

        if (mat < 2) {     // T as [n][c']
            #pragma unroll
            for (int st = 0; st < 4; ++st)
                #pragma unroll
                for (int r = 0; r < 4; ++r)
                    T[(16 * g + 4 * l4 + r) * 68 + 16 * st + l15] = acc[st][r];
        } else {           // v: T as [c'][n]
            #pragma unroll
            for (int st = 0; st < 4; ++st)
                #pragma unroll
                for (int r = 0; r < 4; ++r)
                    T[(16 * st + l15) * 68 + 16 * g + 4 * l4 + r] = acc[st][r];
        }
        __syncthreads();

        const int row = t >> 2;            // n (q/k) or c' (v)
        const int sg  = 16 * (t & 3);
        const float4 a0 = *(const float4*)&T[row * 68 + sg + 0];
        const float4 a1 = *(const float4*)&T[row * 68 + sg + 4];
        const float4 a2 = *(const float4*)&T[row * 68 + sg + 8];
        const float4 a3 = *(const float4*)&T[row * 68 + sg + 12];
        const uint4 lo = make_uint4(pk_trunc(a0.x, a0.y), pk_trunc(a0.z, a0.w),
                                    pk_trunc(a1.x, a1.y), pk_trunc(a1.z, a1.w));
        const uint4 hi = make_uint4(pk_trunc(a2.x, a2.y), pk_trunc(a2.z, a2.w),
                                    pk_trunc(a3.x, a3.y), pk_trunc(a3.z, a3.w));
        unsigned short* dst;
        if (mat < 2) {
            dst = (mat == 0 ? qT : kT) + ((size_t)(b * Nn + n0 + row)) * CPd + sg;
        } else {
            dst = vB + ((size_t)(b * CPd + row)) * Nn + n0 + sg;
        }
        *(uint4*)dst = lo;
        *(uint4*)(dst + 8) = hi;
    }
}

// ------------------------------------------------------------ flash (MFMA) --
// 8 waves x 16 Q-rows = 128-row Q block. K/V double-buffered in four
// statically-named LDS arrays: STAGE(next) issued before COMPUTE(cur); the
// single __syncthreads per tile both drains the (long-issued) stage and
// fences the buffer overwrite. P is wave-private in Pb -> no barrier between
// P write and PV read. S pre-scaled by log2e -> exp is one native exp2.
__global__ __launch_bounds__(512, 6) void flash_kernel(
    const unsigned short* __restrict__ qT, const unsigned short* __restrict__ kT,
    const unsigned short* __restrict__ vB, float* __restrict__ Op, float* __restrict__ Lg)
{
    __shared__ __align__(16) unsigned short Ks0[TIL * 64];  // [m][c'] swizzled, 8 KB
    __shared__ __align__(16) unsigned short Ks1[TIL * 64];
    __shared__ __align__(16) unsigned short Vs0[TIL * 64];  // [c'][m] swizzled, 8 KB
    __shared__ __align__(16) unsigned short Vs1[TIL * 64];
    __shared__ __align__(16) unsigned Pb[QROWS * 34];       // bf16-pair [n][m/2], 17.4 KB

    const int b   = blockIdx.y;
    const int n0  = blockIdx.x * QROWS;
    const int s   = blockIdx.z;
    const int t   = threadIdx.x;     // 0..511
    const int l   = t & 63;
    const int w   = t >> 6;          // 8 waves, 16 q-rows each
    const int l15 = l & 15;
    const int l4  = l >> 4;
    const int par = l & 1;
    const unsigned sel = par ? 0x03020706u : 0x07060302u;
    const int l15h = l15 >> 1;

    // Q A-frags straight from global
    const unsigned short* qp = qT + (size_t)(b * Nn + n0 + 16 * w + l15) * CPd + 8 * l4;
    const short8 qf0 = *(const short8*)qp;
    const short8 qf1 = *(const short8*)(qp + 32);

    f32x4 acco[4];
    #pragma unroll
    for (int ct = 0; ct < 4; ++ct) acco[ct] = (f32x4){0.f, 0.f, 0.f, 0.f};
    float Lp[4] = {0.f, 0.f, 0.f, 0.f};

    // staging geometry: wave w stages K rows [8w,8w+8) and V rows [8w,8w+8);
    // lane covers row 8w + (l>>3), LDS chunk l&7 <- source chunk (l&7)^(row&7)
    const int r8  = l >> 3;               // 0..7 (== row&7)
    const int sch = (l & 7) ^ r8;
    const unsigned short* kPtr = kT + (size_t)b * Nn * CPd
                               + (size_t)(8 * w + r8) * CPd + 8 * sch;
    const unsigned short* vPtr = vB + (size_t)b * CPd * Nn
                               + (size_t)(8 * w + r8) * Nn + 8 * sch;
    const int ldsOff = 8 * w * 64;        // wave-uniform LDS base (lane adds l*16B)

    // read-side swizzle: chunk c at row r lives at chunk c^(r&7)
    const int h7  = l15 & 7;
    const int sw0 = (l4 ^ h7) << 4;       // byte offset of chunk, ks=0 (ks=1: ^64)

    const int mbase = s * MQUAR;
    const int nt = MQUAR / TIL;           // 16 (even)

    auto STAGE = [&](unsigned short* KD, unsigned short* VD, int m0) {
        gl16(kPtr + (size_t)m0 * CPd, KD + ldsOff);
        gl16(vPtr + m0,               VD + ldsOff);
    };
    auto COMPUTE = [&](const unsigned short* Kb, const unsigned short* Vb) {
        const char* KsB = (const char*)Kb + (l15 << 7);
        const char* VsB = (const char*)Vb + (l15 << 7);
        // ---- S' = log2e * (Q^T K): 4 chains x 2 k-steps ----
        f32x4 accs[4];
        #pragma unroll
        for (int st = 0; st < 4; ++st) {
            accs[st] = (f32x4){0.f, 0.f, 0.f, 0.f};
            const short8 kf0 = *(const short8*)(KsB + (st << 11) + sw0);
            const short8 kf1 = *(const short8*)(KsB + (st << 11) + (sw0 ^ 64));
            accs[st] = __builtin_amdgcn_mfma_f32_16x16x32_bf16(qf0, kf0, accs[st], 0, 0, 0);
            accs[st] = __builtin_amdgcn_mfma_f32_16x16x32_bf16(qf1, kf1, accs[st], 0, 0, 0);
        }
        // ---- P = 2^S'; DPP pair-pack to bf16; wave-private rows of Pb ----
        #pragma unroll
        for (int st = 0; st < 4; ++st) {
            unsigned u[4];
            #pragma unroll
            for (int r = 0; r < 4; ++r) {
                float p = exp2f(accs[st][r]);   // native v_exp_f32
                Lp[r] += p;
                float nb = dpp_swap1(p);
                u[r] = __builtin_amdgcn_perm(__float_as_uint(nb), __float_as_uint(p), sel);
            }
            const int rb = 16 * w + 4 * l4 + 2 * par;  // even lane: rows {0,1}; odd: {2,3}
            Pb[(rb + 0) * 34 + 8 * st + l15h] = u[2 * par];
            Pb[(rb + 1) * 34 + 8 * st + l15h] = u[2 * par + 1];
        }
        // no barrier: wave w reads only Pb rows [16w,16w+16) which it wrote
        #pragma unroll
        for (int ks = 0; ks < 2; ++ks) {
            const short8 pf = *(const short8*)&Pb[(16 * w + l15) * 34 + 4 * l4 + 16 * ks];
            const int swk = sw0 ^ (ks << 6);
            #pragma unroll
            for (int ct = 0; ct < 4; ++ct) {
                const short8 vf = *(const short8*)(VsB + (ct << 11) + swk);
                acco[ct] = __builtin_amdgcn_mfma_f32_16x16x32_bf16(pf, vf, acco[ct], 0, 0, 0);
            }
        }
    };

    STAGE(Ks0, Vs0, mbase);
    __syncthreads();                      // buf0 staged (vmcnt drain + barrier)
    for (int ti = 0; ti < nt; ti += 2) {
        const int m0 = mbase + ti * TIL;
        STAGE(Ks1, Vs1, m0 + TIL);        // issue early: hides under compute
        COMPUTE(Ks0, Vs0);
        __syncthreads();                  // drains (cheap: issued ~1500cy ago); fences buf0
        if (ti + 2 < nt) STAGE(Ks0, Vs0, m0 + 2 * TIL);
        COMPUTE(Ks1, Vs1);
        __syncthreads();
    }

    // ---- epilogue: shuffle-reduce L over the 16 lanes of each row ----
    #pragma unroll
    for (int r = 0; r < 4; ++r) {
        float v = Lp[r];
        v += __shfl_xor(v, 1, 64); v += __shfl_xor(v, 2, 64);
        v += __shfl_xor(v, 4, 64); v += __shfl_xor(v, 8, 64);
        Lp[r] = v;
    }
    if (l15 == 0) {
        #pragma unroll
        for (int r = 0; r < 4; ++r)
            atomicAdd(&Lg[(size_t)b * Nn + n0 + 16 * w + 4 * l4 + r], Lp[r]);
    }
    float* ob = Op + ((size_t)(b * Nn + n0 + 16 * w)) * CPd;
    #pragma unroll
    for (int r = 0; r < 4; ++r) {
        const int nl = 4 * l4 + r;
        #pragma unroll
        for (int ct = 0; ct < 4; ++ct)
            atomicAdd(&ob[(size_t)nl * CPd + 16 * ct + l15], acco[ct][r]);
    }
}

// ------------------------------------------------------- output proj (MFMA) --
__global__ __launch_bounds__(512) void out_kernel(
    const float* __restrict__ Op, const float* __restrict__ Lg,
    const unsigned short* __restrict__ Wob,
    const float* __restrict__ bo, const float* __restrict__ gamma,
    const float* __restrict__ x, float* __restrict__ y)
{
    __shared__ __align__(16) unsigned short Wos[Cch * 72];  // 36 KB
    __shared__ __align__(16) unsigned short Sas[TIL * 72];  // 9 KB
    __shared__ float bos[Cch];

    const int b   = blockIdx.y;
    const int n0  = blockIdx.x * TIL;
    const int t   = threadIdx.x;     // 0..511
    const int l   = t & 63;
    const int w   = t >> 6;          // 8 waves
    const int l15 = l & 15;
    const int l4  = l >> 4;

    if (t < Cch) bos[t] = bo[t];
    {   // Wo bf16: 2048 uint4 / 512 threads = 4 each
        const uint4* wg = (const uint4*)Wob;
        #pragma unroll
        for (int p = 0; p < 4; ++p) {
            const int idx = p * 512 + t;
            const int row = idx >> 3, seg = idx & 7;
            *(uint4*)&Wos[row * 72 + seg * 8] = wg[idx];
        }
    }
    if (t < 256) {   // normalize accumulated partials + pack sa tile to bf16
        const int n = t >> 2, seg = t & 3;
        const float* o0 = Op + ((size_t)(b * Nn + n0 + n)) * CPd + seg * 16;
        const float sc = C2 / Lg[(size_t)b * Nn + n0 + n];
        unsigned pk[8];
        #pragma unroll
        for (int i = 0; i < 4; ++i) {
            const float4 a = ((const float4*)o0)[i];
            pk[2 * i]     = pk_trunc(a.x * sc, a.y * sc);
            pk[2 * i + 1] = pk_trunc(a.z * sc, a.w * sc);
        }
        *(uint4*)&Sas[n * 72 + seg * 16]     = make_uint4(pk[0], pk[1], pk[2], pk[3]);
        *(uint4*)&Sas[n * 72 + seg * 16 + 8] = make_uint4(pk[4], pk[5], pk[6], pk[7]);
    }
    __syncthreads();

    short8 bfr[4][2];
    #pragma unroll
    for (int ns = 0; ns < 4; ++ns) {
        bfr[ns][0] = *(const short8*)&Sas[(16 * ns + l15) * 72 + 8 * l4];
        bfr[ns][1] = *(const short8*)&Sas[(16 * ns + l15) * 72 + 8 * l4 + 32];
    }
    const float gam = gamma[0];
    const float* xb = x + (size_t)b * Cch * Nn;
    float*       yb = y + (size_t)b * Cch * Nn;

    #pragma unroll
    for (int os2 = 0; os2 < 2; ++os2) {
        const int obase = 16 * (w + 8 * os2);     // 16 strips over 8 waves x 2
        const short8 af0 = *(const short8*)&Wos[(obase + l15) * 72 + 8 * l4];
        const short8 af1 = *(const short8*)&Wos[(obase + l15) * 72 + 8 * l4 + 32];
        #pragma unroll
        for (int ns = 0; ns < 4; ++ns) {
            f32x4 acc = (f32x4){0.f, 0.f, 0.f, 0.f};
            acc = __builtin_amdgcn_mfma_f32_16x16x32_bf16(af0, bfr[ns][0], acc, 0, 0, 0);
            acc = __builtin_amdgcn_mfma_f32_16x16x32_bf16(af1, bfr[ns][1], acc, 0, 0, 0);
            #pragma unroll
            for (int r = 0; r < 4; ++r) {
                const int o = obase + 4 * l4 + r;
                const size_t idx = (size_t)o * Nn + n0 + 16 * ns + l15;
                yb[idx] = fmaf(gam, acc[r] + bos[o], xb[idx]);
            }
        }
    }
}

// ---------------------------------------------------------------------------
extern "C" void kernel_launch(void* const* d_in, const int* in_sizes, int n_in,
                              void* d_out, int out_size, void* d_ws, size_t ws_size,
                              hipStream_t stream)
{
    (void)in_sizes; (void)n_in; (void)out_size; (void)ws_size;
    const float* x     = (const float*)d_in[0];
    const float* Wq    = (const float*)d_in[1];
    const float* bq    = (const float*)d_in[2];
    const float* Wk    = (const float*)d_in[3];
    const float* bk    = (const float*)d_in[4];
    const float* Wv    = (const float*)d_in[5];
    const float* bv    = (const float*)d_in[6];
    const float* Wo    = (const float*)d_in[7];
    const float* bo    = (const float*)d_in[8];
    const float* gamma = (const float*)d_in[9];
    float* y = (float*)d_out;

    const size_t per = (size_t)Bsz * Nn * CPd;           // 2,097,152 elements
    unsigned short* qT = (unsigned short*)d_ws;          // 4 MB
    unsigned short* kT = qT + per;                       // 4 MB
    unsigned short* vB = kT + per;                       // 4 MB
    float* Op = (float*)(vB + per);                      // 8 MB: [b][n][c'] f32 accum
    float* Lg = Op + per;                                // 128 KB: [b][n] f32 accum
    unsigned short* Wb = (unsigned short*)(Lg + (size_t)Bsz * Nn);  // 128 KB

    // zero the atomically-accumulated partials (Op + Lg are contiguous)
    hipMemsetAsync(Op, 0, (per + (size_t)Bsz * Nn) * sizeof(float), stream);

    dim3 grid(Nn / TIL, Bsz);
    dim3 gridF(Nn / QROWS, Bsz, NSPL);
    wconv_kernel<<<64, 256, 0, stream>>>(Wq, Wk, Wv, Wo, Wb);
    qkv_kernel<<<grid, 256, 0, stream>>>(x, Wb, bq, bk, bv, qT, kT, vB);
    flash_kernel<<<gridF, 512, 0, stream>>>(qT, kT, vB, Op, Lg);
    out_kernel<<<grid, 512, 0, stream>>>(Op, Lg, Wb + 3 * 16384, bo, gamma, x, y);
}

// Round 7
// 178.684 us; speedup vs baseline: 1.1541x; 1.0665x over previous
//
#include <hip/hip_runtime.h>

// Non-local (SAGAN) block on MI355X. B=8, C=256, C'=64, N=4096.
// Round 13: base = R11 (last proven pass: 190.6us, flash 79.5). Deltas vs R11:
//  - exp path: revert log2e folding; use __expf (v_mul+v_exp, 2 inst, no OCML
//    range handling). Theory: exp2f's ~20-inst OCML body was the VALUBusy=58%.
//  - s_setprio(1) around MFMA clusters (T5; HK-proven, benign).
// wconv + Wb restored exactly as R11 (R12's fold was in the crash bundle).
// ws: qT 4MB | kT 4MB | vB 4MB | Op[b][n][c'] f32 8MB | Lg[b][n] 128KB | Wb 128KB

#define Bsz 8
#define Cch 256
#define CPd 64
#define Nn  4096
#define TIL 64
#define QROWS 128              // flash Q rows per block (8 waves x 16)
#define NSPL 4                 // KV split factor
#define MQUAR (Nn / NSPL)      // 1024

typedef __attribute__((ext_vector_type(8))) short short8;   // 8 bf16 (MFMA A/B frag)
typedef __attribute__((ext_vector_type(4))) float f32x4;    // 16x16 C/D frag

static constexpr float C1 = (float)(1.41421 / 16.0);  // ROOT_2/sqrt(C)
static constexpr float C2 = (float)(1.41421 / 8.0);   // ROOT_2/sqrt(C')

__device__ inline unsigned pk_trunc(float lo, float hi) { // -> bf16x2 (truncate), 1 v_perm
    return __builtin_amdgcn_perm(__float_as_uint(hi), __float_as_uint(lo), 0x07060302u);
}
__device__ inline float dpp_swap1(float v) {  // lane l <-> l^1 (quad_perm [1,0,3,2])
    return __uint_as_float((unsigned)__builtin_amdgcn_mov_dpp(
        (int)__float_as_uint(v), 0xB1, 0xF, 0xF, true));
}
__device__ __forceinline__ void gl16(const unsigned short* g, unsigned short* s) {
    __builtin_amdgcn_global_load_lds(
        (const __attribute__((address_space(1))) void*)g,
        (__attribute__((address_space(3))) void*)s, 16, 0, 0);
}

// -------------------------------------------------------- W f32->bf16 conv --
__global__ __launch_bounds__(256) void wconv_kernel(
    const float* __restrict__ Wq, const float* __restrict__ Wk,
    const float* __restrict__ Wv, const float* __restrict__ Wo,
    unsigned short* __restrict__ Wb)
{
    const int idx = (blockIdx.x * 256 + threadIdx.x) * 4;   // grid 64 -> 65536 elements
    const float* src = (idx < 16384) ? Wq : (idx < 32768) ? Wk : (idx < 49152) ? Wv : Wo;
    const float4 v = *(const float4*)(src + (idx & 16383));
    *(uint2*)(Wb + idx) = make_uint2(pk_trunc(v.x, v.y), pk_trunc(v.z, v.w));
}

// --------------------------------------------------------- QKV proj (MFMA) --
__global__ __launch_bounds__(256) void qkv_kernel(
    const float* __restrict__ x, const unsigned short* __restrict__ Wb,
    const float* __restrict__ bq, const float* __restrict__ bk, const float* __restrict__ bv,
    unsigned short* __restrict__ qT, unsigned short* __restrict__ kT,
    unsigned short* __restrict__ vB)
{
    __shared__ __align__(16) unsigned short Wlds[CPd * 264];  // [o][c] bf16 (33 KB)
    __shared__ __align__(16) float T[TIL * 68];               // 17.4 KB

    const int b   = blockIdx.y;
    const int n0  = blockIdx.x * TIL;
    const int t   = threadIdx.x;
    const int g   = t >> 6;
    const int l15 = t & 15;
    const int l4  = (t & 63) >> 4;

    // A-frags from global x: lane row n = n0+16g+l15, k = c = 8*l4 + j + 32*ks
    const float* xb = x + (size_t)b * Cch * Nn + n0 + 16 * g + l15;
    short8 xf[8];
    #pragma unroll
    for (int ks = 0; ks < 8; ++ks) {
        float xr[8];
        #pragma unroll
        for (int j = 0; j < 8; ++j)
            xr[j] = C1 * xb[(size_t)(8 * l4 + 32 * ks + j) * Nn];
        union { unsigned u[4]; short8 s; } p;
        p.u[0] = pk_trunc(xr[0], xr[1]); p.u[1] = pk_trunc(xr[2], xr[3]);
        p.u[2] = pk_trunc(xr[4], xr[5]); p.u[3] = pk_trunc(xr[6], xr[7]);
        xf[ks] = p.s;
    }

    #pragma unroll
    for (int mat = 0; mat < 3; ++mat) {
        {   // stage W[64][256] bf16 = 2048 uint4, coalesced, 8 per thread
            const uint4* wg = (const uint4*)(Wb + mat * 16384);
            #pragma unroll
            for (int p = 0; p < 8; ++p) {
                const int idx = p * 256 + t;
                const int o = idx >> 5, cs = idx & 31;
                *(uint4*)&Wlds[o * 264 + cs * 8] = wg[idx];
            }
        }
        __syncthreads();   // W staged

        const float* bias = (mat == 0) ? bq : (mat == 1) ? bk : bv;
        f32x4 acc[4];
        #pragma unroll
        for (int st = 0; st < 4; ++st) {
            const float bb = bias[16 * st + l15];
            acc[st] = (f32x4){bb, bb, bb, bb};
        }
        #pragma unroll
        for (int st = 0; st < 4; ++st) {
            #pragma unroll
            for (int ks = 0; ks < 8; ++ks) {
                const short8 wf = *(const short8*)&Wlds[(16 * st + l15) * 264 + 8 * l4 + 32 * ks];
                acc[st] = __builtin_amdgcn_mfma_f32_16x16x32_bf16(xf[ks], wf, acc[st], 0, 0, 0);
            }
        }
        __syncthreads();   // all Wlds reads done (next mat may restage)

        if (mat < 2) {     // T as [n][c']
            #pragma unroll
            for (int st = 0; st < 4; ++st)
                #pragma unroll
                for (int r = 0; r < 4; ++r)
                    T[(16 * g + 4 * l4 + r) * 68 + 16 * st + l15] = acc[st][r];
        } else {           // v: T as [c'][n]
            #pragma unroll
            for (int st = 0; st < 4; ++st)
                #pragma unroll
                for (int r = 0; r < 4; ++r)
                    T[(16 * st + l15) * 68 + 16 * g + 4 * l4 + r] = acc[st][r];
        }
        __syncthreads();

        const int row = t >> 2;            // n (q/k) or c' (v)
        const int sg  = 16 * (t & 3);
        const float4 a0 = *(const float4*)&T[row * 68 + sg + 0];
        const float4 a1 = *(const float4*)&T[row * 68 + sg + 4];
        const float4 a2 = *(const float4*)&T[row * 68 + sg + 8];
        const float4 a3 = *(const float4*)&T[row * 68 + sg + 12];
        const uint4 lo = make_uint4(pk_trunc(a0.x, a0.y), pk_trunc(a0.z, a0.w),
                                    pk_trunc(a1.x, a1.y), pk_trunc(a1.z, a1.w));
        const uint4 hi = make_uint4(pk_trunc(a2.x, a2.y), pk_trunc(a2.z, a2.w),
                                    pk_trunc(a3.x, a3.y), pk_trunc(a3.z, a3.w));
        unsigned short* dst;
        if (mat < 2) {
            dst = (mat == 0 ? qT : kT) + ((size_t)(b * Nn + n0 + row)) * CPd + sg;
        } else {
            dst = vB + ((size_t)(b * CPd + row)) * Nn + n0 + sg;
        }
        *(uint4*)dst = lo;
        *(uint4*)(dst + 8) = hi;
    }
}

// ------------------------------------------------------------ flash (MFMA) --
// 8 waves x 16 Q-rows = 128-row Q block. K/V double-buffered in four
// statically-named LDS arrays: STAGE(next) issued before COMPUTE(cur); one
// __syncthreads per tile drains the long-issued stage and fences the buffer.
// P is wave-private in Pb -> no P barrier. exp via __expf (2 inst, fast).
// s_setprio(1) around MFMA clusters (T5).
__global__ __launch_bounds__(512, 6) void flash_kernel(
    const unsigned short* __restrict__ qT, const unsigned short* __restrict__ kT,
    const unsigned short* __restrict__ vB, float* __restrict__ Op, float* __restrict__ Lg)
{
    __shared__ __align__(16) unsigned short Ks0[TIL * 64];  // [m][c'] swizzled, 8 KB
    __shared__ __align__(16) unsigned short Ks1[TIL * 64];
    __shared__ __align__(16) unsigned short Vs0[TIL * 64];  // [c'][m] swizzled, 8 KB
    __shared__ __align__(16) unsigned short Vs1[TIL * 64];
    __shared__ __align__(16) unsigned Pb[QROWS * 34];       // bf16-pair [n][m/2], 17.4 KB

    const int b   = blockIdx.y;
    const int n0  = blockIdx.x * QROWS;
    const int s   = blockIdx.z;
    const int t   = threadIdx.x;     // 0..511
    const int l   = t & 63;
    const int w   = t >> 6;          // 8 waves, 16 q-rows each
    const int l15 = l & 15;
    const int l4  = l >> 4;
    const int par = l & 1;
    const unsigned sel = par ? 0x03020706u : 0x07060302u;
    const int l15h = l15 >> 1;

    // Q A-frags straight from global
    const unsigned short* qp = qT + (size_t)(b * Nn + n0 + 16 * w + l15) * CPd + 8 * l4;
    const short8 qf0 = *(const short8*)qp;
    const short8 qf1 = *(const short8*)(qp + 32);

    f32x4 acco[4];
    #pragma unroll
    for (int ct = 0; ct < 4; ++ct) acco[ct] = (f32x4){0.f, 0.f, 0.f, 0.f};
    float Lp[4] = {0.f, 0.f, 0.f, 0.f};

    // staging geometry: wave w stages K rows [8w,8w+8) and V rows [8w,8w+8);
    // lane covers row 8w + (l>>3), LDS chunk l&7 <- source chunk (l&7)^(row&7)
    const int r8  = l >> 3;               // 0..7 (== row&7)
    const int sch = (l & 7) ^ r8;
    const unsigned short* kPtr = kT + (size_t)b * Nn * CPd
                               + (size_t)(8 * w + r8) * CPd + 8 * sch;
    const unsigned short* vPtr = vB + (size_t)b * CPd * Nn
                               + (size_t)(8 * w + r8) * Nn + 8 * sch;
    const int ldsOff = 8 * w * 64;        // wave-uniform LDS base (lane adds l*16B)

    // read-side swizzle: chunk c at row r lives at chunk c^(r&7)
    const int h7  = l15 & 7;
    const int sw0 = (l4 ^ h7) << 4;       // byte offset of chunk, ks=0 (ks=1: ^64)

    const int mbase = s * MQUAR;
    const int nt = MQUAR / TIL;           // 16 (even)

    auto STAGE = [&](unsigned short* KD, unsigned short* VD, int m0) {
        gl16(kPtr + (size_t)m0 * CPd, KD + ldsOff);
        gl16(vPtr + m0,               VD + ldsOff);
    };
    auto COMPUTE = [&](const unsigned short* Kb, const unsigned short* Vb) {
        const char* KsB = (const char*)Kb + (l15 << 7);
        const char* VsB = (const char*)Vb + (l15 << 7);
        // ---- S = Q^T K: 4 chains x 2 k-steps ----
        f32x4 accs[4];
        __builtin_amdgcn_s_setprio(1);
        #pragma unroll
        for (int st = 0; st < 4; ++st) {
            accs[st] = (f32x4){0.f, 0.f, 0.f, 0.f};
            const short8 kf0 = *(const short8*)(KsB + (st << 11) + sw0);
            const short8 kf1 = *(const short8*)(KsB + (st << 11) + (sw0 ^ 64));
            accs[st] = __builtin_amdgcn_mfma_f32_16x16x32_bf16(qf0, kf0, accs[st], 0, 0, 0);
            accs[st] = __builtin_amdgcn_mfma_f32_16x16x32_bf16(qf1, kf1, accs[st], 0, 0, 0);
        }
        __builtin_amdgcn_s_setprio(0);
        // ---- P = exp(S) via __expf (v_mul+v_exp); DPP pair-pack to bf16 ----
        #pragma unroll
        for (int st = 0; st < 4; ++st) {
            unsigned u[4];
            #pragma unroll
            for (int r = 0; r < 4; ++r) {
                float p = __expf(accs[st][r]);
                Lp[r] += p;
                float nb = dpp_swap1(p);
                u[r] = __builtin_amdgcn_perm(__float_as_uint(nb), __float_as_uint(p), sel);
            }
            const int rb = 16 * w + 4 * l4 + 2 * par;  // even lane: rows {0,1}; odd: {2,3}
            Pb[(rb + 0) * 34 + 8 * st + l15h] = u[2 * par];
            Pb[(rb + 1) * 34 + 8 * st + l15h] = u[2 * par + 1];
        }
        // no barrier: wave w reads only Pb rows [16w,16w+16) which it wrote
        __builtin_amdgcn_s_setprio(1);
        #pragma unroll
        for (int ks = 0; ks < 2; ++ks) {
            const short8 pf = *(const short8*)&Pb[(16 * w + l15) * 34 + 4 * l4 + 16 * ks];
            const int swk = sw0 ^ (ks << 6);
            #pragma unroll
            for (int ct = 0; ct < 4; ++ct) {
                const short8 vf = *(const short8*)(VsB + (ct << 11) + swk);
                acco[ct] = __builtin_amdgcn_mfma_f32_16x16x32_bf16(pf, vf, acco[ct], 0, 0, 0);
            }
        }
        __builtin_amdgcn_s_setprio(0);
    };

    STAGE(Ks0, Vs0, mbase);
    __syncthreads();                      // buf0 staged (vmcnt drain + barrier)
    for (int ti = 0; ti < nt; ti += 2) {
        const int m0 = mbase + ti * TIL;
        STAGE(Ks1, Vs1, m0 + TIL);        // issue early: hides under compute
        COMPUTE(Ks0, Vs0);
        __syncthreads();                  // drains (cheap: issued ~1500cy ago); fences buf0
        if (ti + 2 < nt) STAGE(Ks0, Vs0, m0 + 2 * TIL);
        COMPUTE(Ks1, Vs1);
        __syncthreads();
    }

    // ---- epilogue: shuffle-reduce L over the 16 lanes of each row ----
    #pragma unroll
    for (int r = 0; r < 4; ++r) {
        float v = Lp[r];
        v += __shfl_xor(v, 1, 64); v += __shfl_xor(v, 2, 64);
        v += __shfl_xor(v, 4, 64); v += __shfl_xor(v, 8, 64);
        Lp[r] = v;
    }
    if (l15 == 0) {
        #pragma unroll
        for (int r = 0; r < 4; ++r)
            atomicAdd(&Lg[(size_t)b * Nn + n0 + 16 * w + 4 * l4 + r], Lp[r]);
    }
    float* ob = Op + ((size_t)(b * Nn + n0 + 16 * w)) * CPd;
    #pragma unroll
    for (int r = 0; r < 4; ++r) {
        const int nl = 4 * l4 + r;
        #pragma unroll
        for (int ct = 0; ct < 4; ++ct)
            atomicAdd(&ob[(size_t)nl * CPd + 16 * ct + l15], acco[ct][r]);
    }
}

// ------------------------------------------------------- output proj (MFMA) --
__global__ __launch_bounds__(512) void out_kernel(
    const float* __restrict__ Op, const float* __restrict__ Lg,
    const unsigned short* __restrict__ Wob,
    const float* __restrict__ bo, const float* __restrict__ gamma,
    const float* __restrict__ x, float* __restrict__ y)
{
    __shared__ __align__(16) unsigned short Wos[Cch * 72];  // 36 KB
    __shared__ __align__(16) unsigned short Sas[TIL * 72];  // 9 KB
    __shared__ float bos[Cch];

    const int b   = blockIdx.y;
    const int n0  = blockIdx.x * TIL;
    const int t   = threadIdx.x;     // 0..511
    const int l   = t & 63;
    const int w   = t >> 6;          // 8 waves
    const int l15 = l & 15;
    const int l4  = l >> 4;

    if (t < Cch) bos[t] = bo[t];
    {   // Wo bf16: 2048 uint4 / 512 threads = 4 each
        const uint4* wg = (const uint4*)Wob;
        #pragma unroll
        for (int p = 0; p < 4; ++p) {
            const int idx = p * 512 + t;
            const int row = idx >> 3, seg = idx & 7;
            *(uint4*)&Wos[row * 72 + seg * 8] = wg[idx];
        }
    }
    if (t < 256) {   // normalize accumulated partials + pack sa tile to bf16
        const int n = t >> 2, seg = t & 3;
        const float* o0 = Op + ((size_t)(b * Nn + n0 + n)) * CPd + seg * 16;
        const float sc = C2 / Lg[(size_t)b * Nn + n0 + n];
        unsigned pk[8];
        #pragma unroll
        for (int i = 0; i < 4; ++i) {
            const float4 a = ((const float4*)o0)[i];
            pk[2 * i]     = pk_trunc(a.x * sc, a.y * sc);
            pk[2 * i + 1] = pk_trunc(a.z * sc, a.w * sc);
        }
        *(uint4*)&Sas[n * 72 + seg * 16]     = make_uint4(pk[0], pk[1], pk[2], pk[3]);
        *(uint4*)&Sas[n * 72 + seg * 16 + 8] = make_uint4(pk[4], pk[5], pk[6], pk[7]);
    }
    __syncthreads();

    short8 bfr[4][2];
    #pragma unroll
    for (int ns = 0; ns < 4; ++ns) {
        bfr[ns][0] = *(const short8*)&Sas[(16 * ns + l15) * 72 + 8 * l4];
        bfr[ns][1] = *(const short8*)&Sas[(16 * ns + l15) * 72 + 8 * l4 + 32];
    }
    const float gam = gamma[0];
    const float* xb = x + (size_t)b * Cch * Nn;
    float*       yb = y + (size_t)b * Cch * Nn;

    #pragma unroll
    for (int os2 = 0; os2 < 2; ++os2) {
        const int obase = 16 * (w + 8 * os2);     // 16 strips over 8 waves x 2
        const short8 af0 = *(const short8*)&Wos[(obase + l15) * 72 + 8 * l4];
        const short8 af1 = *(const short8*)&Wos[(obase + l15) * 72 + 8 * l4 + 32];
        #pragma unroll
        for (int ns = 0; ns < 4; ++ns) {
            f32x4 acc = (f32x4){0.f, 0.f, 0.f, 0.f};
            acc = __builtin_amdgcn_mfma_f32_16x16x32_bf16(af0, bfr[ns][0], acc, 0, 0, 0);
            acc = __builtin_amdgcn_mfma_f32_16x16x32_bf16(af1, bfr[ns][1], acc, 0, 0, 0);
            #pragma unroll
            for (int r = 0; r < 4; ++r) {
                const int o = obase + 4 * l4 + r;
                const size_t idx = (size_t)o * Nn + n0 + 16 * ns + l15;
                yb[idx] = fmaf(gam, acc[r] + bos[o], xb[idx]);
            }
        }
    }
}

// ---------------------------------------------------------------------------
extern "C" void kernel_launch(void* const* d_in, const int* in_sizes, int n_in,
                              void* d_out, int out_size, void* d_ws, size_t ws_size,
                              hipStream_t stream)
{
    (void)in_sizes; (void)n_in; (void)out_size; (void)ws_size;
    const float* x     = (const float*)d_in[0];
    const float* Wq    = (const float*)d_in[1];
    const float* bq    = (const float*)d_in[2];
    const float* Wk    = (const float*)d_in[3];
    const float* bk    = (const float*)d_in[4];
    const float* Wv    = (const float*)d_in[5];
    const float* bv    = (const float*)d_in[6];
    const float* Wo    = (const float*)d_in[7];
    const float* bo    = (const float*)d_in[8];
    const float* gamma = (const float*)d_in[9];
    float* y = (float*)d_out;

    const size_t per = (size_t)Bsz * Nn * CPd;           // 2,097,152 elements
    unsigned short* qT = (unsigned short*)d_ws;          // 4 MB
    unsigned short* kT = qT + per;                       // 4 MB
    unsigned short* vB = kT + per;                       // 4 MB
    float* Op = (float*)(vB + per);                      // 8 MB: [b][n][c'] f32 accum
    float* Lg = Op + per;                                // 128 KB: [b][n] f32 accum
    unsigned short* Wb = (unsigned short*)(Lg + (size_t)Bsz * Nn);  // 128 KB

    // zero the atomically-accumulated partials (Op + Lg are contiguous)
    hipMemsetAsync(Op, 0, (per + (size_t)Bsz * Nn) * sizeof(float), stream);

    dim3 grid(Nn / TIL, Bsz);
    dim3 gridF(Nn / QROWS, Bsz, NSPL);
    wconv_kernel<<<64, 256, 0, stream>>>(Wq, Wk, Wv, Wo, Wb);
    qkv_kernel<<<grid, 256, 0, stream>>>(x, Wb, bq, bk, bv, qT, kT, vB);
    flash_kernel<<<gridF, 512, 0, stream>>>(qT, kT, vB, Op, Lg);
    out_kernel<<<grid, 512, 0, stream>>>(Op, Lg, Wb + 3 * 16384, bo, gamma, x, y);
}